// Round 8
// baseline (1333.475 us; speedup 1.0000x reference)
//
#include <hip/hip_runtime.h>
#include <cmath>

#define Bsz 64
#define Tt  512
#define Dd  768
#define Wn  255
#define Hh  8
#define DHd 96
#define NROWS (Bsz*Wn)   // 16320

typedef _Float16 half_t;
typedef _Float16 f16x8 __attribute__((ext_vector_type(8)));
typedef _Float16 f16x4 __attribute__((ext_vector_type(4)));
typedef float f32x4 __attribute__((ext_vector_type(4)));
typedef float f32x16 __attribute__((ext_vector_type(16)));

// ---- split-fp16 weights (transposed [N][K]), ~27 MiB static device memory ----
// scales: weights x64, activations x16, GEMM epilogue descales by 1/1024.
// QKV hi-planes contiguous (rows: Q 0-767, K 768-1535, V 1536-2303), then lo.
#define OFF_QKV_H 0
#define OFF_QKV_L 1769472
#define OFF_WO_H 3538944
#define OFF_WO_L 4128768
#define OFF_W1_H 4718592
#define OFF_W1_L 7077888
#define OFF_W2_H 9437184
#define OFF_W2_L 11796480
#define SLOTH 25165824        // halves per 48 MiB workspace slot (q16->k16->v16)
__device__ __align__(16) half_t g_w16[14155776];

__device__ __forceinline__ void gload16(const half_t* g, half_t* l) {
    __builtin_amdgcn_global_load_lds((const __attribute__((address_space(1))) void*)g,
                                     (__attribute__((address_space(3))) void*)l, 16, 0, 0);
}

// ---------------- gather: first-subtoken index + feature copy ----------------

__global__ void k_init_fi(int* fi) {
    int i = blockIdx.x * 256 + threadIdx.x;
    if (i < Bsz * Wn) fi[i] = 0x7fffffff;
}

__global__ void k_scan(const int* __restrict__ wid, int* __restrict__ fi) {
    int i = blockIdx.x * 256 + threadIdx.x;   // over B*T
    if (i >= Bsz * Tt) return;
    int b = i / Tt, t = i % Tt;
    int w = wid[i];
    if (w >= 0 && w < Wn) atomicMin(&fi[b * Wn + w], t);
}

__global__ void k_bcat(const float* __restrict__ bq, const float* __restrict__ bk,
                       const float* __restrict__ bv, float* __restrict__ o) {
    int i = blockIdx.x * 256 + threadIdx.x;
    if (i < 768) o[i] = bq[i];
    else if (i < 1536) o[i] = bk[i - 768];
    else if (i < 2304) o[i] = bv[i - 1536];
}

// gather directly into interleaved fp16 hi/lo records (row = 1536 halves: hi[768]|lo[768])
__global__ void k_gather(const float4* __restrict__ ob, const int* __restrict__ fi,
                         half_t* __restrict__ f16) {
    int i = blockIdx.x * 256 + threadIdx.x;   // over NROWS*192
    if (i >= NROWS * 192) return;
    int r = i / 192, c = i % 192;
    int b = r / Wn;
    int idx = fi[r];
    if (idx == 0x7fffffff) idx = 0;           // argmax(all-False) == 0
    float4 v = ob[((size_t)b * Tt + idx) * 192 + c];
    float a0 = v.x * 16.f, a1 = v.y * 16.f, a2 = v.z * 16.f, a3 = v.w * 16.f;
    half_t h0 = (half_t)a0, h1 = (half_t)a1, h2 = (half_t)a2, h3 = (half_t)a3;
    f16x4 hv = {h0, h1, h2, h3};
    f16x4 lv = {(half_t)(a0 - (float)h0), (half_t)(a1 - (float)h1),
                (half_t)(a2 - (float)h2), (half_t)(a3 - (float)h3)};
    size_t off = (size_t)r * 1536 + c * 4;
    *(f16x4*)&f16[off] = hv;
    *(f16x4*)&f16[off + 768] = lv;
}

// ---------------- weight transpose + split: W[K,N] -> WT_h/WT_l [N,K] x64 ----

__global__ void k_wsplit(const float* __restrict__ Wm, int K, int N,
                         size_t off_h, size_t off_l) {
    __shared__ float sm[32][33];
    const int tx = threadIdx.x, ty = threadIdx.y;
    const int n0 = blockIdx.x * 32, k0 = blockIdx.y * 32;
    #pragma unroll
    for (int r = 0; r < 4; ++r)
        sm[ty + r * 8][tx] = Wm[(size_t)(k0 + ty + r * 8) * N + n0 + tx];
    __syncthreads();
    half_t* oh = g_w16 + off_h;
    half_t* ol = g_w16 + off_l;
    #pragma unroll
    for (int r = 0; r < 4; ++r) {
        float v = 64.f * sm[tx][ty + r * 8];
        half_t hi = (half_t)v;
        size_t o = (size_t)(n0 + ty + r * 8) * K + k0 + tx;
        oh[o] = hi;
        ol[o] = (half_t)(v - (float)hi);
    }
}

// ---------------- split-fp16 MFMA GEMM, 32x32x16 inner tile ------------------
// A: hi/lo fp16 (x16). AMODE 0: linear rows, stride lda halves.
//                      AMODE 1: head-major ctx [bh][256][hi96|lo96].
// B: g_w16+boff, [N][K] (x64). C_logical = acc/1024.
// 32x32x16 frag: A/B lane l -> m(or n)=l&31, k=(l>>5)*8+j; C/D: col=l&31,
// row=(r&3)+8*(r>>2)+4*(l>>5)  [HW-verified layout, m74/m101].
// Grid swizzle: xcd = lin&7 gets contiguous row-tiles (needs gridDim.y%8==0).
// MODE 5: fused QKV -> q16/k16/v16 all head-major [bh][256][hi96|lo96]
// MODE 1: fp32 row-major + interleaved fp16-pair residual (O-proj)
// MODE 2: relu -> fp16 hi/lo pair out x16 (FFN1)
// MODE 3: fp32 row-major + fp32 residual (FFN2)

template<int MODE, int AMODE, int NTILE>
__global__ __launch_bounds__(256, 3) void k_gemm16(
    const half_t* __restrict__ Ah, const half_t* __restrict__ Al, int lda,
    size_t boff_h, size_t boff_l,
    const float* __restrict__ bias,
    const void* __restrict__ res,
    void* __restrict__ out0, void* __restrict__ out1,
    int M, int N, int K) {
    constexpr int MI32 = (NTILE == 128 ? 2 : 1);
    __shared__ half_t sA[2][128 * 32];
    __shared__ half_t sB[2][NTILE * 32];
    const int tid = threadIdx.x;
    const int w = tid >> 6, l = tid & 63;
    // XCD-locality swizzle
    int lin = blockIdx.y * gridDim.x + blockIdx.x;
    int rpx = gridDim.y >> 3;                    // row-tiles per XCD
    int j_ = lin >> 3;
    int jr = j_ / gridDim.x;
    int by = (lin & 7) * rpx + jr;
    int bx = j_ - jr * gridDim.x;
    const int row0 = by * 128, col0 = bx * NTILE;
    const half_t* Bh = g_w16 + boff_h;
    const half_t* Bl = g_w16 + boff_l;

    const int srow = l >> 2;            // 0..15 (staging)
    const int skk  = (l & 3) * 8;       // 0,8,16,24 (staging)
    const int m32 = l & 31, kh8 = (l >> 5) * 8;   // fragment addressing
    const int mh = (NTILE == 128) ? (w >> 1) * 64 : w * 32;
    const int nh = (NTILE == 128) ? (w & 1) * 64 : 0;

    f32x16 acc[MI32][2];
    #pragma unroll
    for (int i = 0; i < MI32; ++i)
        #pragma unroll
        for (int j = 0; j < 2; ++j)
            #pragma unroll
            for (int r = 0; r < 16; ++r) acc[i][j][r] = 0.f;

    for (int k0 = 0; k0 < K; k0 += 32) {
        #pragma unroll
        for (int t = 0; t < 2; ++t) {
            int r = (w * 2 + t) * 16 + srow;
            int grA = row0 + r; if (grA >= M) grA = M - 1;
            half_t* da  = (half_t*)&sA[0][(w * 2 + t) * 512];
            half_t* da2 = (half_t*)&sA[1][(w * 2 + t) * 512];
            if (AMODE == 1) {
                int b = grA / 255, wl = grA - b * 255;
                int kk = k0 + skk;
                int h = kk / 96, d = kk - h * 96;
                size_t aoff = ((size_t)(b * 8 + h) * 256 + wl) * 192 + d;
                gload16(Ah + aoff, da);
                gload16(Al + aoff, da2);
            } else {
                gload16(Ah + (size_t)grA * lda + k0 + skk, da);
                gload16(Al + (size_t)grA * lda + k0 + skk, da2);
            }
            if (NTILE == 128 || t == 0) {
                int bs = (NTILE == 128) ? (w * 2 + t) : w;
                int grB = col0 + bs * 16 + srow;
                gload16(Bh + (size_t)grB * K + k0 + skk, (half_t*)&sB[0][bs * 512]);
                gload16(Bl + (size_t)grB * K + k0 + skk, (half_t*)&sB[1][bs * 512]);
            }
        }
        __syncthreads();
        f16x8 a0[MI32][2], a1[MI32][2], b0[2][2], b1[2][2];
        #pragma unroll
        for (int i = 0; i < MI32; ++i)
            #pragma unroll
            for (int h = 0; h < 2; ++h) {
                a0[i][h] = *(const f16x8*)&sA[0][(mh + i * 32 + m32) * 32 + h * 16 + kh8];
                a1[i][h] = *(const f16x8*)&sA[1][(mh + i * 32 + m32) * 32 + h * 16 + kh8];
            }
        #pragma unroll
        for (int j = 0; j < 2; ++j)
            #pragma unroll
            for (int h = 0; h < 2; ++h) {
                b0[j][h] = *(const f16x8*)&sB[0][(nh + j * 32 + m32) * 32 + h * 16 + kh8];
                b1[j][h] = *(const f16x8*)&sB[1][(nh + j * 32 + m32) * 32 + h * 16 + kh8];
            }
        #pragma unroll
        for (int i = 0; i < MI32; ++i)
            #pragma unroll
            for (int j = 0; j < 2; ++j)
                #pragma unroll
                for (int h = 0; h < 2; ++h) {
                    acc[i][j] = __builtin_amdgcn_mfma_f32_32x32x16_f16(a0[i][h], b0[j][h], acc[i][j], 0, 0, 0);
                    acc[i][j] = __builtin_amdgcn_mfma_f32_32x32x16_f16(a0[i][h], b1[j][h], acc[i][j], 0, 0, 0);
                    acc[i][j] = __builtin_amdgcn_mfma_f32_32x32x16_f16(a1[i][h], b0[j][h], acc[i][j], 0, 0, 0);
                }
        __syncthreads();
    }

    const float dsc = 1.0f / 1024.0f;
    #pragma unroll
    for (int i = 0; i < MI32; ++i) {
        #pragma unroll
        for (int r = 0; r < 16; ++r) {
            int row = row0 + mh + i * 32 + (r & 3) + 8 * (r >> 2) + 4 * (l >> 5);
            if (row >= M) continue;
            #pragma unroll
            for (int j = 0; j < 2; ++j) {
                int col = col0 + nh + j * 32 + m32;
                float vv = acc[i][j][r] * dsc + bias[col];
                if (MODE == 5) {
                    int b = row / 255, wl = row - b * 255;
                    int part = col / 768;              // 0=Q,1=K,2=V
                    int cc = col - part * 768;
                    int h = cc / 96, d = cc - h * 96;
                    float t16 = vv * 16.f;
                    half_t hi = (half_t)t16;
                    half_t lo = (half_t)(t16 - (float)hi);
                    half_t* dst = (half_t*)out0 + (size_t)part * SLOTH;
                    size_t o = ((size_t)(b * 8 + h) * 256 + wl) * 192 + d;
                    dst[o] = hi; dst[o + 96] = lo;
                } else if (MODE == 1) {
                    const half_t* rp = (const half_t*)res;
                    vv += ((float)rp[(size_t)row * 1536 + col] +
                           (float)rp[(size_t)row * 1536 + 768 + col]) * 0.0625f;
                    ((float*)out0)[(size_t)row * N + col] = vv;
                } else if (MODE == 2) {
                    vv = fmaxf(vv, 0.f);
                    float t16 = vv * 16.f;
                    half_t hi = (half_t)t16;
                    ((half_t*)out0)[(size_t)row * N + col] = hi;
                    ((half_t*)out1)[(size_t)row * N + col] = (half_t)(t16 - (float)hi);
                } else {
                    vv += ((const float*)res)[(size_t)row * N + col];
                    ((float*)out0)[(size_t)row * N + col] = vv;
                }
            }
        }
    }
}

// ---------------- flash MFMA attention, split-fp16, one block per (b,h) ------
// q/ctx/k/v all: [bh][256][hi96|lo96] x16. V transposed to [dim][key] in LDS
// at staging time. kt-outer / qt-inner in 2 passes.

__global__ __launch_bounds__(256, 2) void k_attn2(half_t* __restrict__ qc,
                                                  const half_t* __restrict__ kk16,
                                                  const half_t* __restrict__ vv16) {
    __shared__ half_t sK[64][200];      // [key][hi96|lo96], pad 200
    __shared__ half_t sVT[192][72];     // [(plane*96+dim)][key64], pad 72
    __shared__ float  sP[4][16][68];    // per-wave P [qrow][key], pad 68
    const int tid = threadIdx.x;
    const int w = tid >> 6, l = tid & 63;
    const int lr = l & 15, lc = l >> 4;
    const size_t base = (size_t)blockIdx.x * 49152;
    const float ssc = 0.10206207261596575f / 256.0f;   // 1/sqrt(96) / (16*16)

    for (int pass = 0; pass < 2; ++pass) {
        f32x4 O[2][6];
        float mrow[2][4], lrow[2][4];
        #pragma unroll
        for (int qs = 0; qs < 2; ++qs) {
            #pragma unroll
            for (int dn = 0; dn < 6; ++dn) O[qs][dn] = (f32x4){0.f, 0.f, 0.f, 0.f};
            #pragma unroll
            for (int r = 0; r < 4; ++r) { mrow[qs][r] = -3e38f; lrow[qs][r] = 0.f; }
        }
        for (int kt = 0; kt < 4; ++kt) {
            __syncthreads();
            #pragma unroll
            for (int c = 0; c < 6; ++c) {
                int ch = w + c * 4;
                *(f16x8*)&sK[l][ch * 8] =
                    *(const f16x8*)(kk16 + base + (size_t)(kt * 64 + l) * 192 + ch * 8);
            }
            #pragma unroll
            for (int c = 0; c < 6; ++c) {
                int ch = w + c * 4;
                f16x8 vv = *(const f16x8*)(vv16 + base + (size_t)(kt * 64 + l) * 192 + ch * 8);
                #pragma unroll
                for (int j = 0; j < 8; ++j) sVT[ch * 8 + j][l] = vv[j];
            }
            __syncthreads();
            #pragma unroll
            for (int qs = 0; qs < 2; ++qs) {
                const int qrow0 = (pass * 2 + qs) * 64 + w * 16;
                f16x8 qf0[3], qf1[3];
                #pragma unroll
                for (int s = 0; s < 3; ++s) {
                    qf0[s] = *(const f16x8*)(qc + base + (size_t)(qrow0 + lr) * 192 + s * 32 + lc * 8);
                    qf1[s] = *(const f16x8*)(qc + base + (size_t)(qrow0 + lr) * 192 + 96 + s * 32 + lc * 8);
                }
                f32x4 sacc[4];
                #pragma unroll
                for (int nt = 0; nt < 4; ++nt) sacc[nt] = (f32x4){0.f, 0.f, 0.f, 0.f};
                #pragma unroll
                for (int s = 0; s < 3; ++s)
                    #pragma unroll
                    for (int nt = 0; nt < 4; ++nt) {
                        f16x8 kh = *(const f16x8*)&sK[nt * 16 + lr][s * 32 + lc * 8];
                        f16x8 klo = *(const f16x8*)&sK[nt * 16 + lr][96 + s * 32 + lc * 8];
                        sacc[nt] = __builtin_amdgcn_mfma_f32_16x16x32_f16(qf0[s], kh, sacc[nt], 0, 0, 0);
                        sacc[nt] = __builtin_amdgcn_mfma_f32_16x16x32_f16(qf0[s], klo, sacc[nt], 0, 0, 0);
                        sacc[nt] = __builtin_amdgcn_mfma_f32_16x16x32_f16(qf1[s], kh, sacc[nt], 0, 0, 0);
                    }
                float sv[4][4], mx[4] = {-3e38f, -3e38f, -3e38f, -3e38f};
                #pragma unroll
                for (int nt = 0; nt < 4; ++nt) {
                    int key = kt * 64 + nt * 16 + lr;
                    #pragma unroll
                    for (int r = 0; r < 4; ++r) {
                        float s_ = sacc[nt][r] * ssc;
                        if (key >= 255) s_ = -3e38f;
                        sv[nt][r] = s_;
                        mx[r] = fmaxf(mx[r], s_);
                    }
                }
                #pragma unroll
                for (int r = 0; r < 4; ++r) {
                    mx[r] = fmaxf(mx[r], __shfl_xor(mx[r], 1));
                    mx[r] = fmaxf(mx[r], __shfl_xor(mx[r], 2));
                    mx[r] = fmaxf(mx[r], __shfl_xor(mx[r], 4));
                    mx[r] = fmaxf(mx[r], __shfl_xor(mx[r], 8));
                }
                float alpha[4], rsum[4];
                #pragma unroll
                for (int r = 0; r < 4; ++r) {
                    float mn = fmaxf(mrow[qs][r], mx[r]);
                    alpha[r] = __expf(mrow[qs][r] - mn);
                    mrow[qs][r] = mn;
                    rsum[r] = 0.f;
                }
                float pv[4][4];
                #pragma unroll
                for (int nt = 0; nt < 4; ++nt)
                    #pragma unroll
                    for (int r = 0; r < 4; ++r) {
                        float p = __expf(sv[nt][r] - mrow[qs][r]);
                        pv[nt][r] = p;
                        rsum[r] += p;
                    }
                #pragma unroll
                for (int r = 0; r < 4; ++r) {
                    rsum[r] += __shfl_xor(rsum[r], 1);
                    rsum[r] += __shfl_xor(rsum[r], 2);
                    rsum[r] += __shfl_xor(rsum[r], 4);
                    rsum[r] += __shfl_xor(rsum[r], 8);
                    lrow[qs][r] = lrow[qs][r] * alpha[r] + rsum[r];
                }
                #pragma unroll
                for (int dn = 0; dn < 6; ++dn)
                    #pragma unroll
                    for (int r = 0; r < 4; ++r) O[qs][dn][r] *= alpha[r];
                #pragma unroll
                for (int nt = 0; nt < 4; ++nt)
                    #pragma unroll
                    for (int r = 0; r < 4; ++r)
                        sP[w][lc * 4 + r][nt * 16 + lr] = pv[nt][r];
                #pragma unroll
                for (int ks = 0; ks < 2; ++ks) {
                    const float* pp = &sP[w][lr][ks * 32 + lc * 8];
                    f16x8 ph, pl;
                    #pragma unroll
                    for (int j = 0; j < 8; ++j) {
                        float p = pp[j];
                        half_t h_ = (half_t)p;
                        ph[j] = h_;
                        pl[j] = (half_t)(p - (float)h_);
                    }
                    #pragma unroll
                    for (int dn = 0; dn < 6; ++dn) {
                        f16x8 vh = *(const f16x8*)&sVT[dn * 16 + lr][ks * 32 + lc * 8];
                        f16x8 vl = *(const f16x8*)&sVT[96 + dn * 16 + lr][ks * 32 + lc * 8];
                        O[qs][dn] = __builtin_amdgcn_mfma_f32_16x16x32_f16(ph, vh, O[qs][dn], 0, 0, 0);
                        O[qs][dn] = __builtin_amdgcn_mfma_f32_16x16x32_f16(ph, vl, O[qs][dn], 0, 0, 0);
                        O[qs][dn] = __builtin_amdgcn_mfma_f32_16x16x32_f16(pl, vh, O[qs][dn], 0, 0, 0);
                    }
                }
            }
        }
        #pragma unroll
        for (int qs = 0; qs < 2; ++qs) {
            const int qrow0 = (pass * 2 + qs) * 64 + w * 16;
            #pragma unroll
            for (int r = 0; r < 4; ++r) {
                int qrow = qrow0 + lc * 4 + r;
                if (qrow >= Wn) continue;
                float inv = 1.0f / lrow[qs][r];
                #pragma unroll
                for (int dn = 0; dn < 6; ++dn) {
                    float val = O[qs][dn][r] * inv;
                    half_t hi = (half_t)val;
                    half_t lo = (half_t)(val - (float)hi);
                    size_t o = base + (size_t)qrow * 192 + dn * 16 + lr;
                    qc[o] = hi;
                    qc[o + 96] = lo;
                }
            }
        }
    }
}

// ---------------- row LayerNorm with fused fp16-pair split output ------------

__global__ __launch_bounds__(256) void k_ln1(const float* __restrict__ X, const float* __restrict__ g,
                                             const float* __restrict__ bt, float* __restrict__ Y,
                                             half_t* __restrict__ Y16) {
    const int r = blockIdx.x, tid = threadIdx.x;
    __shared__ float red[256];
    const float* x = X + (size_t)r * Dd;
    float x0 = x[tid], x1 = x[tid + 256], x2 = x[tid + 512];
    red[tid] = x0 + x1 + x2; __syncthreads();
    for (int s = 128; s > 0; s >>= 1) { if (tid < s) red[tid] += red[tid + s]; __syncthreads(); }
    float mean = red[0] * (1.0f / 768.0f);
    __syncthreads();
    float d0 = x0 - mean, d1 = x1 - mean, d2 = x2 - mean;
    red[tid] = d0 * d0 + d1 * d1 + d2 * d2; __syncthreads();
    for (int s = 128; s > 0; s >>= 1) { if (tid < s) red[tid] += red[tid + s]; __syncthreads(); }
    float rs = rsqrtf(red[0] * (1.0f / 768.0f) + 1e-5f);
    float* y = Y + (size_t)r * Dd;
    float y0 = d0 * rs * g[tid]       + bt[tid];
    float y1 = d1 * rs * g[tid + 256] + bt[tid + 256];
    float y2 = d2 * rs * g[tid + 512] + bt[tid + 512];
    y[tid] = y0; y[tid + 256] = y1; y[tid + 512] = y2;
    half_t* h = Y16 + (size_t)r * 1536;
    float t0 = y0 * 16.f, t1 = y1 * 16.f, t2 = y2 * 16.f;
    half_t h0 = (half_t)t0, h1 = (half_t)t1, h2 = (half_t)t2;
    h[tid] = h0; h[tid + 256] = h1; h[tid + 512] = h2;
    h[768 + tid] = (half_t)(t0 - (float)h0);
    h[768 + tid + 256] = (half_t)(t1 - (float)h1);
    h[768 + tid + 512] = (half_t)(t2 - (float)h2);
}

// -------- fused LN2 + final LN + 2-class linear + softmax + argmax ----------

__global__ __launch_bounds__(256) void k_final2(const float* __restrict__ X,
                                                const float* __restrict__ g2, const float* __restrict__ b2,
                                                const float* __restrict__ ng, const float* __restrict__ nb,
                                                const float* __restrict__ lw, const float* __restrict__ lb,
                                                float* __restrict__ out) {
    const int r = blockIdx.x, tid = threadIdx.x;
    __shared__ float red[256];
    const float* x = X + (size_t)r * Dd;
    float x0 = x[tid], x1 = x[tid + 256], x2 = x[tid + 512];
    // LN2
    red[tid] = x0 + x1 + x2; __syncthreads();
    for (int s = 128; s > 0; s >>= 1) { if (tid < s) red[tid] += red[tid + s]; __syncthreads(); }
    float mean = red[0] * (1.0f / 768.0f);
    __syncthreads();
    float d0 = x0 - mean, d1 = x1 - mean, d2 = x2 - mean;
    red[tid] = d0 * d0 + d1 * d1 + d2 * d2; __syncthreads();
    for (int s = 128; s > 0; s >>= 1) { if (tid < s) red[tid] += red[tid + s]; __syncthreads(); }
    float rs = rsqrtf(red[0] * (1.0f / 768.0f) + 1e-5f);
    __syncthreads();
    float y0 = d0 * rs * g2[tid]       + b2[tid];
    float y1 = d1 * rs * g2[tid + 256] + b2[tid + 256];
    float y2 = d2 * rs * g2[tid + 512] + b2[tid + 512];
    // final LN
    red[tid] = y0 + y1 + y2; __syncthreads();
    for (int s = 128; s > 0; s >>= 1) { if (tid < s) red[tid] += red[tid + s]; __syncthreads(); }
    mean = red[0] * (1.0f / 768.0f);
    __syncthreads();
    float e0 = y0 - mean, e1 = y1 - mean, e2 = y2 - mean;
    red[tid] = e0 * e0 + e1 * e1 + e2 * e2; __syncthreads();
    for (int s = 128; s > 0; s >>= 1) { if (tid < s) red[tid] += red[tid + s]; __syncthreads(); }
    rs = rsqrtf(red[0] * (1.0f / 768.0f) + 1e-5f);
    __syncthreads();
    float n0 = e0 * rs * ng[tid]       + nb[tid];
    float n1 = e1 * rs * ng[tid + 256] + nb[tid + 256];
    float n2 = e2 * rs * ng[tid + 512] + nb[tid + 512];
    float l0 = n0 * lw[2 * tid]     + n1 * lw[2 * (tid + 256)]     + n2 * lw[2 * (tid + 512)];
    float l1 = n0 * lw[2 * tid + 1] + n1 * lw[2 * (tid + 256) + 1] + n2 * lw[2 * (tid + 512) + 1];
    red[tid] = l0; __syncthreads();
    for (int s = 128; s > 0; s >>= 1) { if (tid < s) red[tid] += red[tid + s]; __syncthreads(); }
    l0 = red[0]; __syncthreads();
    red[tid] = l1; __syncthreads();
    for (int s = 128; s > 0; s >>= 1) { if (tid < s) red[tid] += red[tid + s]; __syncthreads(); }
    l1 = red[0];
    if (tid == 0) {
        l0 += lb[0]; l1 += lb[1];
        float m = fmaxf(l0, l1);
        float e0_ = expf(l0 - m), e1_ = expf(l1 - m);
        float inv = 1.0f / (e0_ + e1_);
        out[2 * r] = e0_ * inv;
        out[2 * r + 1] = e1_ * inv;
        out[2 * NROWS + r] = (l1 > l0) ? 1.0f : 0.0f;   // tie -> first index (0)
    }
}

// ---------------- launch --------------------------------------------------

extern "C" void kernel_launch(void* const* d_in, const int* in_sizes, int n_in,
                              void* d_out, int out_size, void* d_ws, size_t ws_size,
                              hipStream_t stream) {
    const float* ob  = (const float*)d_in[0];
    const int*   wid = (const int*)d_in[1];
    const float* Wq  = (const float*)d_in[2];  const float* bq  = (const float*)d_in[3];
    const float* Wk  = (const float*)d_in[4];  const float* bk  = (const float*)d_in[5];
    const float* Wv  = (const float*)d_in[6];  const float* bv  = (const float*)d_in[7];
    const float* Wo  = (const float*)d_in[8];  const float* bo  = (const float*)d_in[9];
    const float* g1  = (const float*)d_in[10]; const float* b1  = (const float*)d_in[11];
    const float* W1f = (const float*)d_in[12]; const float* b1f = (const float*)d_in[13];
    const float* W2f = (const float*)d_in[14]; const float* b2f = (const float*)d_in[15];
    const float* g2  = (const float*)d_in[16]; const float* b2  = (const float*)d_in[17];
    const float* ng  = (const float*)d_in[18]; const float* nb  = (const float*)d_in[19];
    const float* lw  = (const float*)d_in[20]; const float* lb  = (const float*)d_in[21];
    float* out = (float*)d_out;

    char* ws = (char*)d_ws;
    const size_t MB = 1u << 20;
    const size_t SLOT = 48 * MB;               // 50,331,648 B; SLOTH = SLOT/2 halves
    int* fi = (int*)ws;                        // 65,280 B
    float* bcat = (float*)(ws + 262144);       // 2304 floats
    char* S1 = ws + MB;
    char* S2 = S1 + SLOT;
    char* S3 = S2 + SLOT;
    char* S4 = S3 + SLOT;                      // total 193 MiB (proven OK)

    half_t* feat16 = (half_t*)S1;              // interleaved hi|lo, row = 1536 halves
    half_t* q16    = (half_t*)S2;              // [bh][256][192] -> ctx16 in-place
    half_t* k16    = (half_t*)S3;              // [bh][256][192]  (= q16 + SLOTH)
    half_t* v16    = (half_t*)S4;              // [bh][256][192]  (= q16 + 2*SLOTH)
    float*  t1     = (float*)S3;               // Wo out (k16 consumed)
    float*  xbuf   = (float*)S4;               // LN1 out (v16 consumed)
    half_t* x16    = (half_t*)S2;              // LN1 split out (ctx consumed by Wo)
    half_t* ffh_h  = (half_t*)S1;              // per-chunk hidden hi (feat16 consumed)
    half_t* ffh_l  = (half_t*)S3;              // per-chunk hidden lo (t1 consumed)
    float*  t2     = (float*)S2;               // overlays consumed x16 rows (3072 B stride)

    // weight prep: QKV hi contiguous [0,1769472), QKV lo [1769472,3538944)
    k_wsplit<<<dim3(24, 24), dim3(32, 8), 0, stream>>>(Wq, 768, 768, 0, 1769472);
    k_wsplit<<<dim3(24, 24), dim3(32, 8), 0, stream>>>(Wk, 768, 768, 589824, 2359296);
    k_wsplit<<<dim3(24, 24), dim3(32, 8), 0, stream>>>(Wv, 768, 768, 1179648, 2949120);
    k_wsplit<<<dim3(24, 24), dim3(32, 8), 0, stream>>>(Wo, 768, 768, OFF_WO_H, OFF_WO_L);
    k_wsplit<<<dim3(96, 24), dim3(32, 8), 0, stream>>>(W1f, 768, 3072, OFF_W1_H, OFF_W1_L);
    k_wsplit<<<dim3(24, 96), dim3(32, 8), 0, stream>>>(W2f, 3072, 768, OFF_W2_H, OFF_W2_L);
    k_bcat<<<9, 256, 0, stream>>>(bq, bk, bv, bcat);

    k_init_fi<<<(Bsz * Wn + 255) / 256, 256, 0, stream>>>(fi);
    k_scan<<<(Bsz * Tt) / 256, 256, 0, stream>>>(wid, fi);
    k_gather<<<(NROWS * 192 + 255) / 256, 256, 0, stream>>>((const float4*)ob, fi, feat16);

    // fused QKV GEMM -> q16 / k16 / v16 (2304 blocks = 9/CU, XCD-swizzled)
    k_gemm16<5, 0, 128><<<dim3(18, 128), 256, 0, stream>>>(
        feat16, feat16 + 768, 1536, OFF_QKV_H, OFF_QKV_L,
        bcat, nullptr, q16, nullptr, NROWS, 2304, Dd);

    k_attn2<<<Bsz * Hh, 256, 0, stream>>>(q16, k16, v16);     // ctx overwrites q16

    // t1 = feat + ctx@Wo + bo (AMODE 1 gathers head-major ctx) ; x = LN1(t1)
    k_gemm16<1, 1, 128><<<dim3(6, 128), 256, 0, stream>>>(
        q16, q16 + 96, 0, OFF_WO_H, OFF_WO_L,
        bo, feat16, t1, nullptr, NROWS, Dd, Dd);
    k_ln1<<<NROWS, 256, 0, stream>>>(t1, g1, b1, xbuf, x16);

    // FFN in 2 row-chunks of 8160; FFN2 uses 64-wide N tiles (768 blocks = 3/CU)
    for (int c = 0; c < 2; ++c) {
        const int r0 = c * 8160, mc = 8160;
        k_gemm16<2, 0, 128><<<dim3(24, 64), 256, 0, stream>>>(
            x16 + (size_t)r0 * 1536, x16 + (size_t)r0 * 1536 + 768, 1536,
            OFF_W1_H, OFF_W1_L, b1f, nullptr, ffh_h, ffh_l, mc, 3072, Dd);
        k_gemm16<3, 0, 64><<<dim3(12, 64), 256, 0, stream>>>(
            ffh_h, ffh_l, 3072, OFF_W2_H, OFF_W2_L, b2f, xbuf + (size_t)r0 * Dd,
            t2 + (size_t)r0 * Dd, nullptr, mc, Dd, 3072);
    }

    // fused LN2 + final LN + linear + softmax + argmax
    k_final2<<<NROWS, 256, 0, stream>>>(t2, g2, b2, ng, nb, lw, lb, out);
}

// Round 9
// 1256.201 us; speedup vs baseline: 1.0615x; 1.0615x over previous
//
#include <hip/hip_runtime.h>
#include <cmath>

#define Bsz 64
#define Tt  512
#define Dd  768
#define Wn  255
#define Hh  8
#define DHd 96
#define NROWS (Bsz*Wn)   // 16320

typedef _Float16 half_t;
typedef _Float16 f16x8 __attribute__((ext_vector_type(8)));
typedef _Float16 f16x4 __attribute__((ext_vector_type(4)));
typedef float f32x4 __attribute__((ext_vector_type(4)));

// ---- split-fp16 weights (transposed [N][K]), ~27 MiB static device memory ----
// scales: weights x64, activations x16, GEMM epilogue descales by 1/1024.
// QKV hi-planes contiguous (rows: Q 0-767, K 768-1535, V 1536-2303), then lo.
#define OFF_QKV_H 0
#define OFF_QKV_L 1769472
#define OFF_WO_H 3538944
#define OFF_WO_L 4128768
#define OFF_W1_H 4718592
#define OFF_W1_L 7077888
#define OFF_W2_H 9437184
#define OFF_W2_L 11796480
#define SLOTH 25165824        // halves per 48 MiB workspace slot (q16->k16->v16)
__device__ __align__(16) half_t g_w16[14155776];

__device__ __forceinline__ void gload16(const half_t* g, half_t* l) {
    __builtin_amdgcn_global_load_lds((const __attribute__((address_space(1))) void*)g,
                                     (__attribute__((address_space(3))) void*)l, 16, 0, 0);
}

// ---------------- gather: first-subtoken index + feature copy ----------------

__global__ void k_init_fi(int* fi) {
    int i = blockIdx.x * 256 + threadIdx.x;
    if (i < Bsz * Wn) fi[i] = 0x7fffffff;
}

__global__ void k_scan(const int* __restrict__ wid, int* __restrict__ fi) {
    int i = blockIdx.x * 256 + threadIdx.x;   // over B*T
    if (i >= Bsz * Tt) return;
    int b = i / Tt, t = i % Tt;
    int w = wid[i];
    if (w >= 0 && w < Wn) atomicMin(&fi[b * Wn + w], t);
}

__global__ void k_bcat(const float* __restrict__ bq, const float* __restrict__ bk,
                       const float* __restrict__ bv, float* __restrict__ o) {
    int i = blockIdx.x * 256 + threadIdx.x;
    if (i < 768) o[i] = bq[i];
    else if (i < 1536) o[i] = bk[i - 768];
    else if (i < 2304) o[i] = bv[i - 1536];
}

// gather directly into interleaved fp16 hi/lo records (row = 1536 halves: hi[768]|lo[768])
__global__ void k_gather(const float4* __restrict__ ob, const int* __restrict__ fi,
                         half_t* __restrict__ f16) {
    int i = blockIdx.x * 256 + threadIdx.x;   // over NROWS*192
    if (i >= NROWS * 192) return;
    int r = i / 192, c = i % 192;
    int b = r / Wn;
    int idx = fi[r];
    if (idx == 0x7fffffff) idx = 0;           // argmax(all-False) == 0
    float4 v = ob[((size_t)b * Tt + idx) * 192 + c];
    float a0 = v.x * 16.f, a1 = v.y * 16.f, a2 = v.z * 16.f, a3 = v.w * 16.f;
    half_t h0 = (half_t)a0, h1 = (half_t)a1, h2 = (half_t)a2, h3 = (half_t)a3;
    f16x4 hv = {h0, h1, h2, h3};
    f16x4 lv = {(half_t)(a0 - (float)h0), (half_t)(a1 - (float)h1),
                (half_t)(a2 - (float)h2), (half_t)(a3 - (float)h3)};
    size_t off = (size_t)r * 1536 + c * 4;
    *(f16x4*)&f16[off] = hv;
    *(f16x4*)&f16[off + 768] = lv;
}

// ---------------- weight transpose + split: W[K,N] -> WT_h/WT_l [N,K] x64 ----

__global__ void k_wsplit(const float* __restrict__ Wm, int K, int N,
                         size_t off_h, size_t off_l) {
    __shared__ float sm[32][33];
    const int tx = threadIdx.x, ty = threadIdx.y;
    const int n0 = blockIdx.x * 32, k0 = blockIdx.y * 32;
    #pragma unroll
    for (int r = 0; r < 4; ++r)
        sm[ty + r * 8][tx] = Wm[(size_t)(k0 + ty + r * 8) * N + n0 + tx];
    __syncthreads();
    half_t* oh = g_w16 + off_h;
    half_t* ol = g_w16 + off_l;
    #pragma unroll
    for (int r = 0; r < 4; ++r) {
        float v = 64.f * sm[tx][ty + r * 8];
        half_t hi = (half_t)v;
        size_t o = (size_t)(n0 + ty + r * 8) * K + k0 + tx;
        oh[o] = hi;
        ol[o] = (half_t)(v - (float)hi);
    }
}

// ---------------- split-fp16 MFMA GEMM (16x16x32 — round-7 proven config) ----
// NOTE (round 8 post-mortem): 32x32x16 inner tile regressed 3x on
// SQ_LDS_BANK_CONFLICT — its 32-row x 64B-stride fragment read aliases banks
// with period 2 and global_load_lds's fixed wave-uniform dest layout cannot
// be XOR-swizzled to fix it. Keep 16x16.
// A: hi/lo fp16 (x16). AMODE 0: linear rows, stride lda halves.
//                      AMODE 1: head-major ctx [bh][256][hi96|lo96].
// B: g_w16+boff, [N][K] (x64). C_logical = acc/1024.
// Grid swizzle: xcd = lin&7 gets contiguous row-tiles (needs gridDim.y%8==0).
// MODE 5: fused QKV -> q16/k16/v16 all head-major [bh][256][hi96|lo96]
// MODE 1: fp32 row-major + interleaved fp16-pair residual (O-proj)
// MODE 2: relu -> fp16 hi/lo pair out x16 (FFN1)
// MODE 3: fp32 row-major + fp32 residual (FFN2)

template<int MODE, int AMODE, int NTILE>
__global__ __launch_bounds__(256, NTILE == 64 ? 3 : 2) void k_gemm16(
    const half_t* __restrict__ Ah, const half_t* __restrict__ Al, int lda,
    size_t boff_h, size_t boff_l,
    const float* __restrict__ bias,
    const void* __restrict__ res,
    void* __restrict__ out0, void* __restrict__ out1,
    int M, int N, int K) {
    constexpr int MI = (NTILE == 128 ? 4 : 2);
    __shared__ half_t sA[2][128 * 32];
    __shared__ half_t sB[2][NTILE * 32];
    const int tid = threadIdx.x;
    const int w = tid >> 6, l = tid & 63;
    // XCD-locality swizzle
    int lin = blockIdx.y * gridDim.x + blockIdx.x;
    int rpx = gridDim.y >> 3;                    // row-tiles per XCD
    int j_ = lin >> 3;
    int jr = j_ / gridDim.x;
    int by = (lin & 7) * rpx + jr;
    int bx = j_ - jr * gridDim.x;
    const int row0 = by * 128, col0 = bx * NTILE;
    const half_t* Bh = g_w16 + boff_h;
    const half_t* Bl = g_w16 + boff_l;

    const int srow = l >> 2;            // 0..15
    const int skk  = (l & 3) * 8;       // 0,8,16,24
    const int fr = l & 15, qk = (l >> 4) * 8;
    const int mh = (NTILE == 128) ? (w >> 1) * 64 : w * 32;
    const int nh = (NTILE == 128) ? (w & 1) * 64 : 0;

    f32x4 acc[MI][4];
    #pragma unroll
    for (int i = 0; i < MI; ++i)
        #pragma unroll
        for (int j = 0; j < 4; ++j) acc[i][j] = (f32x4){0.f, 0.f, 0.f, 0.f};

    for (int k0 = 0; k0 < K; k0 += 32) {
        #pragma unroll
        for (int t = 0; t < 2; ++t) {
            int r = (w * 2 + t) * 16 + srow;
            int grA = row0 + r; if (grA >= M) grA = M - 1;
            half_t* da  = (half_t*)&sA[0][(w * 2 + t) * 512];
            half_t* da2 = (half_t*)&sA[1][(w * 2 + t) * 512];
            if (AMODE == 1) {
                int b = grA / 255, wl = grA - b * 255;
                int kk = k0 + skk;
                int h = kk / 96, d = kk - h * 96;
                size_t aoff = ((size_t)(b * 8 + h) * 256 + wl) * 192 + d;
                gload16(Ah + aoff, da);
                gload16(Al + aoff, da2);
            } else {
                gload16(Ah + (size_t)grA * lda + k0 + skk, da);
                gload16(Al + (size_t)grA * lda + k0 + skk, da2);
            }
            if (NTILE == 128 || t == 0) {
                int bs = (NTILE == 128) ? (w * 2 + t) : w;
                int grB = col0 + bs * 16 + srow;
                gload16(Bh + (size_t)grB * K + k0 + skk, (half_t*)&sB[0][bs * 512]);
                gload16(Bl + (size_t)grB * K + k0 + skk, (half_t*)&sB[1][bs * 512]);
            }
        }
        __syncthreads();
        f16x8 a0[MI], a1[MI], b0[4], b1[4];
        #pragma unroll
        for (int i = 0; i < MI; ++i) {
            a0[i] = *(const f16x8*)&sA[0][(mh + i * 16 + fr) * 32 + qk];
            a1[i] = *(const f16x8*)&sA[1][(mh + i * 16 + fr) * 32 + qk];
        }
        #pragma unroll
        for (int j = 0; j < 4; ++j) {
            b0[j] = *(const f16x8*)&sB[0][(nh + j * 16 + fr) * 32 + qk];
            b1[j] = *(const f16x8*)&sB[1][(nh + j * 16 + fr) * 32 + qk];
        }
        #pragma unroll
        for (int i = 0; i < MI; ++i)
            #pragma unroll
            for (int j = 0; j < 4; ++j) {
                acc[i][j] = __builtin_amdgcn_mfma_f32_16x16x32_f16(a0[i], b0[j], acc[i][j], 0, 0, 0);
                acc[i][j] = __builtin_amdgcn_mfma_f32_16x16x32_f16(a0[i], b1[j], acc[i][j], 0, 0, 0);
                acc[i][j] = __builtin_amdgcn_mfma_f32_16x16x32_f16(a1[i], b0[j], acc[i][j], 0, 0, 0);
            }
        __syncthreads();
    }

    const float dsc = 1.0f / 1024.0f;
    #pragma unroll
    for (int i = 0; i < MI; ++i) {
        #pragma unroll
        for (int r = 0; r < 4; ++r) {
            int row = row0 + mh + i * 16 + ((l >> 4) << 2) + r;
            if (row >= M) continue;
            #pragma unroll
            for (int j = 0; j < 4; ++j) {
                int col = col0 + nh + j * 16 + (l & 15);
                float vv = acc[i][j][r] * dsc + bias[col];
                if (MODE == 5) {
                    int b = row / 255, wl = row - b * 255;
                    int part = col / 768;              // 0=Q,1=K,2=V
                    int cc = col - part * 768;
                    int h = cc / 96, d = cc - h * 96;
                    float t16 = vv * 16.f;
                    half_t hi = (half_t)t16;
                    half_t lo = (half_t)(t16 - (float)hi);
                    half_t* dst = (half_t*)out0 + (size_t)part * SLOTH;
                    size_t o = ((size_t)(b * 8 + h) * 256 + wl) * 192 + d;
                    dst[o] = hi; dst[o + 96] = lo;
                } else if (MODE == 1) {
                    const half_t* rp = (const half_t*)res;
                    vv += ((float)rp[(size_t)row * 1536 + col] +
                           (float)rp[(size_t)row * 1536 + 768 + col]) * 0.0625f;
                    ((float*)out0)[(size_t)row * N + col] = vv;
                } else if (MODE == 2) {
                    vv = fmaxf(vv, 0.f);
                    float t16 = vv * 16.f;
                    half_t hi = (half_t)t16;
                    ((half_t*)out0)[(size_t)row * N + col] = hi;
                    ((half_t*)out1)[(size_t)row * N + col] = (half_t)(t16 - (float)hi);
                } else {
                    vv += ((const float*)res)[(size_t)row * N + col];
                    ((float*)out0)[(size_t)row * N + col] = vv;
                }
            }
        }
    }
}

// ---------------- flash MFMA attention, split-fp16, one block per (b,h) ------
// q/ctx/k/v all: [bh][256][hi96|lo96] x16. V transposed to [dim][key] in LDS
// at staging time. kt-outer / qt-inner in 2 passes.

__global__ __launch_bounds__(256, 2) void k_attn2(half_t* __restrict__ qc,
                                                  const half_t* __restrict__ kk16,
                                                  const half_t* __restrict__ vv16) {
    __shared__ half_t sK[64][200];      // [key][hi96|lo96], pad 200
    __shared__ half_t sVT[192][72];     // [(plane*96+dim)][key64], pad 72
    __shared__ float  sP[4][16][68];    // per-wave P [qrow][key], pad 68
    const int tid = threadIdx.x;
    const int w = tid >> 6, l = tid & 63;
    const int lr = l & 15, lc = l >> 4;
    const size_t base = (size_t)blockIdx.x * 49152;
    const float ssc = 0.10206207261596575f / 256.0f;   // 1/sqrt(96) / (16*16)

    for (int pass = 0; pass < 2; ++pass) {
        f32x4 O[2][6];
        float mrow[2][4], lrow[2][4];
        #pragma unroll
        for (int qs = 0; qs < 2; ++qs) {
            #pragma unroll
            for (int dn = 0; dn < 6; ++dn) O[qs][dn] = (f32x4){0.f, 0.f, 0.f, 0.f};
            #pragma unroll
            for (int r = 0; r < 4; ++r) { mrow[qs][r] = -3e38f; lrow[qs][r] = 0.f; }
        }
        for (int kt = 0; kt < 4; ++kt) {
            __syncthreads();
            #pragma unroll
            for (int c = 0; c < 6; ++c) {
                int ch = w + c * 4;
                *(f16x8*)&sK[l][ch * 8] =
                    *(const f16x8*)(kk16 + base + (size_t)(kt * 64 + l) * 192 + ch * 8);
            }
            #pragma unroll
            for (int c = 0; c < 6; ++c) {
                int ch = w + c * 4;
                f16x8 vv = *(const f16x8*)(vv16 + base + (size_t)(kt * 64 + l) * 192 + ch * 8);
                #pragma unroll
                for (int j = 0; j < 8; ++j) sVT[ch * 8 + j][l] = vv[j];
            }
            __syncthreads();
            #pragma unroll
            for (int qs = 0; qs < 2; ++qs) {
                const int qrow0 = (pass * 2 + qs) * 64 + w * 16;
                f16x8 qf0[3], qf1[3];
                #pragma unroll
                for (int s = 0; s < 3; ++s) {
                    qf0[s] = *(const f16x8*)(qc + base + (size_t)(qrow0 + lr) * 192 + s * 32 + lc * 8);
                    qf1[s] = *(const f16x8*)(qc + base + (size_t)(qrow0 + lr) * 192 + 96 + s * 32 + lc * 8);
                }
                f32x4 sacc[4];
                #pragma unroll
                for (int nt = 0; nt < 4; ++nt) sacc[nt] = (f32x4){0.f, 0.f, 0.f, 0.f};
                #pragma unroll
                for (int s = 0; s < 3; ++s)
                    #pragma unroll
                    for (int nt = 0; nt < 4; ++nt) {
                        f16x8 kh = *(const f16x8*)&sK[nt * 16 + lr][s * 32 + lc * 8];
                        f16x8 klo = *(const f16x8*)&sK[nt * 16 + lr][96 + s * 32 + lc * 8];
                        sacc[nt] = __builtin_amdgcn_mfma_f32_16x16x32_f16(qf0[s], kh, sacc[nt], 0, 0, 0);
                        sacc[nt] = __builtin_amdgcn_mfma_f32_16x16x32_f16(qf0[s], klo, sacc[nt], 0, 0, 0);
                        sacc[nt] = __builtin_amdgcn_mfma_f32_16x16x32_f16(qf1[s], kh, sacc[nt], 0, 0, 0);
                    }
                float sv[4][4], mx[4] = {-3e38f, -3e38f, -3e38f, -3e38f};
                #pragma unroll
                for (int nt = 0; nt < 4; ++nt) {
                    int key = kt * 64 + nt * 16 + lr;
                    #pragma unroll
                    for (int r = 0; r < 4; ++r) {
                        float s_ = sacc[nt][r] * ssc;
                        if (key >= 255) s_ = -3e38f;
                        sv[nt][r] = s_;
                        mx[r] = fmaxf(mx[r], s_);
                    }
                }
                #pragma unroll
                for (int r = 0; r < 4; ++r) {
                    mx[r] = fmaxf(mx[r], __shfl_xor(mx[r], 1));
                    mx[r] = fmaxf(mx[r], __shfl_xor(mx[r], 2));
                    mx[r] = fmaxf(mx[r], __shfl_xor(mx[r], 4));
                    mx[r] = fmaxf(mx[r], __shfl_xor(mx[r], 8));
                }
                float alpha[4], rsum[4];
                #pragma unroll
                for (int r = 0; r < 4; ++r) {
                    float mn = fmaxf(mrow[qs][r], mx[r]);
                    alpha[r] = __expf(mrow[qs][r] - mn);
                    mrow[qs][r] = mn;
                    rsum[r] = 0.f;
                }
                float pv[4][4];
                #pragma unroll
                for (int nt = 0; nt < 4; ++nt)
                    #pragma unroll
                    for (int r = 0; r < 4; ++r) {
                        float p = __expf(sv[nt][r] - mrow[qs][r]);
                        pv[nt][r] = p;
                        rsum[r] += p;
                    }
                #pragma unroll
                for (int r = 0; r < 4; ++r) {
                    rsum[r] += __shfl_xor(rsum[r], 1);
                    rsum[r] += __shfl_xor(rsum[r], 2);
                    rsum[r] += __shfl_xor(rsum[r], 4);
                    rsum[r] += __shfl_xor(rsum[r], 8);
                    lrow[qs][r] = lrow[qs][r] * alpha[r] + rsum[r];
                }
                #pragma unroll
                for (int dn = 0; dn < 6; ++dn)
                    #pragma unroll
                    for (int r = 0; r < 4; ++r) O[qs][dn][r] *= alpha[r];
                #pragma unroll
                for (int nt = 0; nt < 4; ++nt)
                    #pragma unroll
                    for (int r = 0; r < 4; ++r)
                        sP[w][lc * 4 + r][nt * 16 + lr] = pv[nt][r];
                #pragma unroll
                for (int ks = 0; ks < 2; ++ks) {
                    const float* pp = &sP[w][lr][ks * 32 + lc * 8];
                    f16x8 ph, pl;
                    #pragma unroll
                    for (int j = 0; j < 8; ++j) {
                        float p = pp[j];
                        half_t h_ = (half_t)p;
                        ph[j] = h_;
                        pl[j] = (half_t)(p - (float)h_);
                    }
                    #pragma unroll
                    for (int dn = 0; dn < 6; ++dn) {
                        f16x8 vh = *(const f16x8*)&sVT[dn * 16 + lr][ks * 32 + lc * 8];
                        f16x8 vl = *(const f16x8*)&sVT[96 + dn * 16 + lr][ks * 32 + lc * 8];
                        O[qs][dn] = __builtin_amdgcn_mfma_f32_16x16x32_f16(ph, vh, O[qs][dn], 0, 0, 0);
                        O[qs][dn] = __builtin_amdgcn_mfma_f32_16x16x32_f16(ph, vl, O[qs][dn], 0, 0, 0);
                        O[qs][dn] = __builtin_amdgcn_mfma_f32_16x16x32_f16(pl, vh, O[qs][dn], 0, 0, 0);
                    }
                }
            }
        }
        #pragma unroll
        for (int qs = 0; qs < 2; ++qs) {
            const int qrow0 = (pass * 2 + qs) * 64 + w * 16;
            #pragma unroll
            for (int r = 0; r < 4; ++r) {
                int qrow = qrow0 + lc * 4 + r;
                if (qrow >= Wn) continue;
                float inv = 1.0f / lrow[qs][r];
                #pragma unroll
                for (int dn = 0; dn < 6; ++dn) {
                    float val = O[qs][dn][r] * inv;
                    half_t hi = (half_t)val;
                    half_t lo = (half_t)(val - (float)hi);
                    size_t o = base + (size_t)qrow * 192 + dn * 16 + lr;
                    qc[o] = hi;
                    qc[o + 96] = lo;
                }
            }
        }
    }
}

// ---------------- row LayerNorm with fused fp16-pair split output ------------

__global__ __launch_bounds__(256) void k_ln1(const float* __restrict__ X, const float* __restrict__ g,
                                             const float* __restrict__ bt, float* __restrict__ Y,
                                             half_t* __restrict__ Y16) {
    const int r = blockIdx.x, tid = threadIdx.x;
    __shared__ float red[256];
    const float* x = X + (size_t)r * Dd;
    float x0 = x[tid], x1 = x[tid + 256], x2 = x[tid + 512];
    red[tid] = x0 + x1 + x2; __syncthreads();
    for (int s = 128; s > 0; s >>= 1) { if (tid < s) red[tid] += red[tid + s]; __syncthreads(); }
    float mean = red[0] * (1.0f / 768.0f);
    __syncthreads();
    float d0 = x0 - mean, d1 = x1 - mean, d2 = x2 - mean;
    red[tid] = d0 * d0 + d1 * d1 + d2 * d2; __syncthreads();
    for (int s = 128; s > 0; s >>= 1) { if (tid < s) red[tid] += red[tid + s]; __syncthreads(); }
    float rs = rsqrtf(red[0] * (1.0f / 768.0f) + 1e-5f);
    float* y = Y + (size_t)r * Dd;
    float y0 = d0 * rs * g[tid]       + bt[tid];
    float y1 = d1 * rs * g[tid + 256] + bt[tid + 256];
    float y2 = d2 * rs * g[tid + 512] + bt[tid + 512];
    y[tid] = y0; y[tid + 256] = y1; y[tid + 512] = y2;
    half_t* h = Y16 + (size_t)r * 1536;
    float t0 = y0 * 16.f, t1 = y1 * 16.f, t2 = y2 * 16.f;
    half_t h0 = (half_t)t0, h1 = (half_t)t1, h2 = (half_t)t2;
    h[tid] = h0; h[tid + 256] = h1; h[tid + 512] = h2;
    h[768 + tid] = (half_t)(t0 - (float)h0);
    h[768 + tid + 256] = (half_t)(t1 - (float)h1);
    h[768 + tid + 512] = (half_t)(t2 - (float)h2);
}

// -------- fused LN2 + final LN + 2-class linear + softmax + argmax ----------

__global__ __launch_bounds__(256) void k_final2(const float* __restrict__ X,
                                                const float* __restrict__ g2, const float* __restrict__ b2,
                                                const float* __restrict__ ng, const float* __restrict__ nb,
                                                const float* __restrict__ lw, const float* __restrict__ lb,
                                                float* __restrict__ out) {
    const int r = blockIdx.x, tid = threadIdx.x;
    __shared__ float red[256];
    const float* x = X + (size_t)r * Dd;
    float x0 = x[tid], x1 = x[tid + 256], x2 = x[tid + 512];
    // LN2
    red[tid] = x0 + x1 + x2; __syncthreads();
    for (int s = 128; s > 0; s >>= 1) { if (tid < s) red[tid] += red[tid + s]; __syncthreads(); }
    float mean = red[0] * (1.0f / 768.0f);
    __syncthreads();
    float d0 = x0 - mean, d1 = x1 - mean, d2 = x2 - mean;
    red[tid] = d0 * d0 + d1 * d1 + d2 * d2; __syncthreads();
    for (int s = 128; s > 0; s >>= 1) { if (tid < s) red[tid] += red[tid + s]; __syncthreads(); }
    float rs = rsqrtf(red[0] * (1.0f / 768.0f) + 1e-5f);
    __syncthreads();
    float y0 = d0 * rs * g2[tid]       + b2[tid];
    float y1 = d1 * rs * g2[tid + 256] + b2[tid + 256];
    float y2 = d2 * rs * g2[tid + 512] + b2[tid + 512];
    // final LN
    red[tid] = y0 + y1 + y2; __syncthreads();
    for (int s = 128; s > 0; s >>= 1) { if (tid < s) red[tid] += red[tid + s]; __syncthreads(); }
    mean = red[0] * (1.0f / 768.0f);
    __syncthreads();
    float e0 = y0 - mean, e1 = y1 - mean, e2 = y2 - mean;
    red[tid] = e0 * e0 + e1 * e1 + e2 * e2; __syncthreads();
    for (int s = 128; s > 0; s >>= 1) { if (tid < s) red[tid] += red[tid + s]; __syncthreads(); }
    rs = rsqrtf(red[0] * (1.0f / 768.0f) + 1e-5f);
    __syncthreads();
    float n0 = e0 * rs * ng[tid]       + nb[tid];
    float n1 = e1 * rs * ng[tid + 256] + nb[tid + 256];
    float n2 = e2 * rs * ng[tid + 512] + nb[tid + 512];
    float l0 = n0 * lw[2 * tid]     + n1 * lw[2 * (tid + 256)]     + n2 * lw[2 * (tid + 512)];
    float l1 = n0 * lw[2 * tid + 1] + n1 * lw[2 * (tid + 256) + 1] + n2 * lw[2 * (tid + 512) + 1];
    red[tid] = l0; __syncthreads();
    for (int s = 128; s > 0; s >>= 1) { if (tid < s) red[tid] += red[tid + s]; __syncthreads(); }
    l0 = red[0]; __syncthreads();
    red[tid] = l1; __syncthreads();
    for (int s = 128; s > 0; s >>= 1) { if (tid < s) red[tid] += red[tid + s]; __syncthreads(); }
    l1 = red[0];
    if (tid == 0) {
        l0 += lb[0]; l1 += lb[1];
        float m = fmaxf(l0, l1);
        float e0_ = expf(l0 - m), e1_ = expf(l1 - m);
        float inv = 1.0f / (e0_ + e1_);
        out[2 * r] = e0_ * inv;
        out[2 * r + 1] = e1_ * inv;
        out[2 * NROWS + r] = (l1 > l0) ? 1.0f : 0.0f;   // tie -> first index (0)
    }
}

// ---------------- launch --------------------------------------------------

extern "C" void kernel_launch(void* const* d_in, const int* in_sizes, int n_in,
                              void* d_out, int out_size, void* d_ws, size_t ws_size,
                              hipStream_t stream) {
    const float* ob  = (const float*)d_in[0];
    const int*   wid = (const int*)d_in[1];
    const float* Wq  = (const float*)d_in[2];  const float* bq  = (const float*)d_in[3];
    const float* Wk  = (const float*)d_in[4];  const float* bk  = (const float*)d_in[5];
    const float* Wv  = (const float*)d_in[6];  const float* bv  = (const float*)d_in[7];
    const float* Wo  = (const float*)d_in[8];  const float* bo  = (const float*)d_in[9];
    const float* g1  = (const float*)d_in[10]; const float* b1  = (const float*)d_in[11];
    const float* W1f = (const float*)d_in[12]; const float* b1f = (const float*)d_in[13];
    const float* W2f = (const float*)d_in[14]; const float* b2f = (const float*)d_in[15];
    const float* g2  = (const float*)d_in[16]; const float* b2  = (const float*)d_in[17];
    const float* ng  = (const float*)d_in[18]; const float* nb  = (const float*)d_in[19];
    const float* lw  = (const float*)d_in[20]; const float* lb  = (const float*)d_in[21];
    float* out = (float*)d_out;

    char* ws = (char*)d_ws;
    const size_t MB = 1u << 20;
    const size_t SLOT = 48 * MB;               // 50,331,648 B; SLOTH = SLOT/2 halves
    int* fi = (int*)ws;                        // 65,280 B
    float* bcat = (float*)(ws + 262144);       // 2304 floats
    char* S1 = ws + MB;
    char* S2 = S1 + SLOT;
    char* S3 = S2 + SLOT;
    char* S4 = S3 + SLOT;                      // total 193 MiB (proven OK)

    half_t* feat16 = (half_t*)S1;              // interleaved hi|lo, row = 1536 halves
    half_t* q16    = (half_t*)S2;              // [bh][256][192] -> ctx16 in-place
    half_t* k16    = (half_t*)S3;              // [bh][256][192]  (= q16 + SLOTH)
    half_t* v16    = (half_t*)S4;              // [bh][256][192]  (= q16 + 2*SLOTH)
    float*  t1     = (float*)S3;               // Wo out (k16 consumed)
    float*  xbuf   = (float*)S4;               // LN1 out (v16 consumed)
    half_t* x16    = (half_t*)S2;              // LN1 split out (ctx consumed by Wo)
    half_t* ffh_h  = (half_t*)S1;              // per-chunk hidden hi (feat16 consumed)
    half_t* ffh_l  = (half_t*)S3;              // per-chunk hidden lo (t1 consumed)
    float*  t2     = (float*)S2;               // overlays consumed x16 rows (3072 B stride)

    // weight prep: QKV hi contiguous [0,1769472), QKV lo [1769472,3538944)
    k_wsplit<<<dim3(24, 24), dim3(32, 8), 0, stream>>>(Wq, 768, 768, 0, 1769472);
    k_wsplit<<<dim3(24, 24), dim3(32, 8), 0, stream>>>(Wk, 768, 768, 589824, 2359296);
    k_wsplit<<<dim3(24, 24), dim3(32, 8), 0, stream>>>(Wv, 768, 768, 1179648, 2949120);
    k_wsplit<<<dim3(24, 24), dim3(32, 8), 0, stream>>>(Wo, 768, 768, OFF_WO_H, OFF_WO_L);
    k_wsplit<<<dim3(96, 24), dim3(32, 8), 0, stream>>>(W1f, 768, 3072, OFF_W1_H, OFF_W1_L);
    k_wsplit<<<dim3(24, 96), dim3(32, 8), 0, stream>>>(W2f, 3072, 768, OFF_W2_H, OFF_W2_L);
    k_bcat<<<9, 256, 0, stream>>>(bq, bk, bv, bcat);

    k_init_fi<<<(Bsz * Wn + 255) / 256, 256, 0, stream>>>(fi);
    k_scan<<<(Bsz * Tt) / 256, 256, 0, stream>>>(wid, fi);
    k_gather<<<(NROWS * 192 + 255) / 256, 256, 0, stream>>>((const float4*)ob, fi, feat16);

    // fused QKV GEMM -> q16 / k16 / v16 (2304 blocks = 9/CU, XCD-swizzled)
    k_gemm16<5, 0, 128><<<dim3(18, 128), 256, 0, stream>>>(
        feat16, feat16 + 768, 1536, OFF_QKV_H, OFF_QKV_L,
        bcat, nullptr, q16, nullptr, NROWS, 2304, Dd);

    k_attn2<<<Bsz * Hh, 256, 0, stream>>>(q16, k16, v16);     // ctx overwrites q16

    // t1 = feat + ctx@Wo + bo (AMODE 1 gathers head-major ctx) ; x = LN1(t1)
    k_gemm16<1, 1, 128><<<dim3(6, 128), 256, 0, stream>>>(
        q16, q16 + 96, 0, OFF_WO_H, OFF_WO_L,
        bo, feat16, t1, nullptr, NROWS, Dd, Dd);
    k_ln1<<<NROWS, 256, 0, stream>>>(t1, g1, b1, xbuf, x16);

    // FFN in 2 row-chunks of 8160; FFN2 uses 64-wide N tiles (768 blocks = 3/CU)
    for (int c = 0; c < 2; ++c) {
        const int r0 = c * 8160, mc = 8160;
        k_gemm16<2, 0, 128><<<dim3(24, 64), 256, 0, stream>>>(
            x16 + (size_t)r0 * 1536, x16 + (size_t)r0 * 1536 + 768, 1536,
            OFF_W1_H, OFF_W1_L, b1f, nullptr, ffh_h, ffh_l, mc, 3072, Dd);
        k_gemm16<3, 0, 64><<<dim3(12, 64), 256, 0, stream>>>(
            ffh_h, ffh_l, 3072, OFF_W2_H, OFF_W2_L, b2f, xbuf + (size_t)r0 * Dd,
            t2 + (size_t)r0 * Dd, nullptr, mc, Dd, 3072);
    }

    // fused LN2 + final LN + linear + softmax + argmax
    k_final2<<<NROWS, 256, 0, stream>>>(t2, g2, b2, ng, nb, lw, lb, out);
}